// Round 1
// baseline (5508.990 us; speedup 1.0000x reference)
//
#include <hip/hip_runtime.h>

#define M_NODES 100000
#define N_EDGES 3200000
#define D 128

// ---------------- GEMM: support = x @ W  (M x 128) ----------------
// 64-row x 128-col tile per block, BK=32, 256 threads, 8x4 acc per thread.
__global__ __launch_bounds__(256) void gemm_kernel(const float* __restrict__ x,
                                                   const float* __restrict__ w,
                                                   float* __restrict__ support,
                                                   int M) {
    __shared__ float sX[32][64];    // [k][row] transposed, 8 KB
    __shared__ float sW[32][128];   // [k][col], 16 KB

    const int tid = threadIdx.x;
    const int r0  = blockIdx.x * 64;
    const int tx  = tid & 31;   // col group: cols tx*4 .. tx*4+3
    const int ty  = tid >> 5;   // row group: rows ty*8 .. ty*8+7

    float acc[8][4];
#pragma unroll
    for (int r = 0; r < 8; ++r)
#pragma unroll
        for (int c = 0; c < 4; ++c) acc[r][c] = 0.f;

    for (int c0 = 0; c0 < 128; c0 += 32) {
        // stage x chunk transposed: rows r0..r0+63, k c0..c0+31
        {
            const int row = tid >> 3;          // 0..31
            const int kk  = (tid & 7) * 4;
#pragma unroll
            for (int h = 0; h < 2; ++h) {
                const int rr = row + h * 32;
                float4 v = make_float4(0.f, 0.f, 0.f, 0.f);
                if (r0 + rr < M)
                    v = *(const float4*)&x[(size_t)(r0 + rr) * D + c0 + kk];
                sX[kk + 0][rr] = v.x;
                sX[kk + 1][rr] = v.y;
                sX[kk + 2][rr] = v.z;
                sX[kk + 3][rr] = v.w;
            }
        }
        // stage W chunk: k c0..c0+31, all 128 cols
#pragma unroll
        for (int i = tid; i < 1024; i += 256) {
            const int k  = i >> 5;
            const int c4 = (i & 31) * 4;
            *(float4*)&sW[k][c4] = *(const float4*)&w[(size_t)(c0 + k) * D + c4];
        }
        __syncthreads();

#pragma unroll
        for (int k = 0; k < 32; ++k) {
            const float4 wv = *(const float4*)&sW[k][tx * 4];
            const float4 xa = *(const float4*)&sX[k][ty * 8];
            const float4 xb = *(const float4*)&sX[k][ty * 8 + 4];
            const float xr[8] = {xa.x, xa.y, xa.z, xa.w, xb.x, xb.y, xb.z, xb.w};
#pragma unroll
            for (int r = 0; r < 8; ++r) {
                acc[r][0] += xr[r] * wv.x;
                acc[r][1] += xr[r] * wv.y;
                acc[r][2] += xr[r] * wv.z;
                acc[r][3] += xr[r] * wv.w;
            }
        }
        __syncthreads();
    }

#pragma unroll
    for (int r = 0; r < 8; ++r) {
        const int row = r0 + ty * 8 + r;
        if (row < M)
            *(float4*)&support[(size_t)row * D + tx * 4] =
                make_float4(acc[r][0], acc[r][1], acc[r][2], acc[r][3]);
    }
}

// ---------------- SpMM scatter: out[dst] += support[src] * val ----------------
// 32 threads per edge, float4 per thread, scalar f32 atomics.
__global__ __launch_bounds__(256) void spmm_kernel(const float* __restrict__ support,
                                                   const int* __restrict__ rows,
                                                   const int* __restrict__ cols,
                                                   const float* __restrict__ vals,
                                                   float* __restrict__ out) {
    const long long t = (long long)blockIdx.x * 256 + threadIdx.x;
    const int e = (int)(t >> 5);
    if (e >= N_EDGES) return;
    const int f   = (int)(t & 31) * 4;
    const int src = cols[e];
    const int dst = rows[e];
    const float v = vals[e];
    const float4 s = *(const float4*)&support[(size_t)src * D + f];
    float* o = &out[(size_t)dst * D + f];
    atomicAdd(o + 0, s.x * v);
    atomicAdd(o + 1, s.y * v);
    atomicAdd(o + 2, s.z * v);
    atomicAdd(o + 3, s.w * v);
}

// ---------------- finalize: out = out / norm + bias ----------------
__global__ __launch_bounds__(256) void finalize_kernel(float* __restrict__ out,
                                                       const float* __restrict__ norm,
                                                       const float* __restrict__ bias) {
    const int t = blockIdx.x * 256 + threadIdx.x;   // over M*32 float4 slots
    const int nrow = t >> 5;
    if (nrow >= M_NODES) return;
    const int f = (t & 31) * 4;
    const float inv = 1.0f / norm[nrow];
    float4 o = *(float4*)&out[(size_t)nrow * D + f];
    const float4 b = *(const float4*)&bias[f];
    o.x = o.x * inv + b.x;
    o.y = o.y * inv + b.y;
    o.z = o.z * inv + b.z;
    o.w = o.w * inv + b.w;
    *(float4*)&out[(size_t)nrow * D + f] = o;
}

extern "C" void kernel_launch(void* const* d_in, const int* in_sizes, int n_in,
                              void* d_out, int out_size, void* d_ws, size_t ws_size,
                              hipStream_t stream) {
    const float* x    = (const float*)d_in[0];
    const float* w    = (const float*)d_in[1];
    const float* bias = (const float*)d_in[2];
    const int*   rows = (const int*)d_in[3];
    const int*   cols = (const int*)d_in[4];
    const float* vals = (const float*)d_in[5];
    const float* norm = (const float*)d_in[6];
    float* out     = (float*)d_out;
    float* support = (float*)d_ws;   // 100000*128 fp32 = 51.2 MB

    // out accumulates via atomics; harness poisons it, so zero first.
    hipMemsetAsync(d_out, 0, (size_t)out_size * sizeof(float), stream);

    gemm_kernel<<<(M_NODES + 63) / 64, 256, 0, stream>>>(x, w, support, M_NODES);

    const long long spmm_threads = (long long)N_EDGES * 32;
    spmm_kernel<<<(int)((spmm_threads + 255) / 256), 256, 0, stream>>>(support, rows, cols, vals, out);

    finalize_kernel<<<(M_NODES * 32 + 255) / 256, 256, 0, stream>>>(out, norm, bias);
}

// Round 2
// 720.183 us; speedup vs baseline: 7.6494x; 7.6494x over previous
//
#include <hip/hip_runtime.h>

#define M_NODES 100000
#define N_EDGES 3200000
#define D 128

// ---------------- workspace layout (bytes, 256-aligned) ----------------
#define OFF_SUPPORT 0ull           // 100000*128 f32 = 51,200,000
#define OFF_CNT     51200000ull    // 100000 int     =    400,000 (+pad)
#define OFF_START   51600128ull    // 100001 int     =    400,004 (+pad)
#define OFF_POS     52000256ull    // 100000 int     =    400,000 (+pad)
#define OFF_SRC     52400384ull    // 3.2M int       = 12,800,000
#define OFF_VAL     65200384ull    // 3.2M f32       = 12,800,000
#define OFF_BSUM    78000384ull    // 391 int (+pad)
#define WS_NEEDED   78002432ull

#define NBLK_SCAN 391   // ceil(100000/256)

// ---------------- GEMM: support = x @ W  (M x 128) ----------------
__global__ __launch_bounds__(256) void gemm_kernel(const float* __restrict__ x,
                                                   const float* __restrict__ w,
                                                   float* __restrict__ support,
                                                   int M) {
    __shared__ float sX[32][64];
    __shared__ float sW[32][128];

    const int tid = threadIdx.x;
    const int r0  = blockIdx.x * 64;
    const int tx  = tid & 31;
    const int ty  = tid >> 5;

    float acc[8][4];
#pragma unroll
    for (int r = 0; r < 8; ++r)
#pragma unroll
        for (int c = 0; c < 4; ++c) acc[r][c] = 0.f;

    for (int c0 = 0; c0 < 128; c0 += 32) {
        {
            const int row = tid >> 3;
            const int kk  = (tid & 7) * 4;
#pragma unroll
            for (int h = 0; h < 2; ++h) {
                const int rr = row + h * 32;
                float4 v = make_float4(0.f, 0.f, 0.f, 0.f);
                if (r0 + rr < M)
                    v = *(const float4*)&x[(size_t)(r0 + rr) * D + c0 + kk];
                sX[kk + 0][rr] = v.x;
                sX[kk + 1][rr] = v.y;
                sX[kk + 2][rr] = v.z;
                sX[kk + 3][rr] = v.w;
            }
        }
#pragma unroll
        for (int i = tid; i < 1024; i += 256) {
            const int k  = i >> 5;
            const int c4 = (i & 31) * 4;
            *(float4*)&sW[k][c4] = *(const float4*)&w[(size_t)(c0 + k) * D + c4];
        }
        __syncthreads();

#pragma unroll
        for (int k = 0; k < 32; ++k) {
            const float4 wv = *(const float4*)&sW[k][tx * 4];
            const float4 xa = *(const float4*)&sX[k][ty * 8];
            const float4 xb = *(const float4*)&sX[k][ty * 8 + 4];
            const float xr[8] = {xa.x, xa.y, xa.z, xa.w, xb.x, xb.y, xb.z, xb.w};
#pragma unroll
            for (int r = 0; r < 8; ++r) {
                acc[r][0] += xr[r] * wv.x;
                acc[r][1] += xr[r] * wv.y;
                acc[r][2] += xr[r] * wv.z;
                acc[r][3] += xr[r] * wv.w;
            }
        }
        __syncthreads();
    }

#pragma unroll
    for (int r = 0; r < 8; ++r) {
        const int row = r0 + ty * 8 + r;
        if (row < M)
            *(float4*)&support[(size_t)row * D + tx * 4] =
                make_float4(acc[r][0], acc[r][1], acc[r][2], acc[r][3]);
    }
}

// ---------------- CSR build: histogram ----------------
__global__ __launch_bounds__(256) void hist_kernel(const int* __restrict__ rows,
                                                   int* __restrict__ cnt) {
    const int e = blockIdx.x * 256 + threadIdx.x;
    if (e < N_EDGES) atomicAdd(&cnt[rows[e]], 1);
}

// ---------------- scan step 1: per-block sums ----------------
__global__ __launch_bounds__(256) void scan1_kernel(const int* __restrict__ cnt,
                                                    int* __restrict__ bsum) {
    __shared__ int s[256];
    const int i = blockIdx.x * 256 + threadIdx.x;
    s[threadIdx.x] = (i < M_NODES) ? cnt[i] : 0;
    __syncthreads();
    for (int off = 128; off > 0; off >>= 1) {
        if (threadIdx.x < off) s[threadIdx.x] += s[threadIdx.x + off];
        __syncthreads();
    }
    if (threadIdx.x == 0) bsum[blockIdx.x] = s[0];
}

// ---------------- scan step 2: scan block sums (single block) ----------------
__global__ __launch_bounds__(512) void scan2_kernel(int* __restrict__ bsum, int nb) {
    __shared__ int s[512];
    const int t = threadIdx.x;
    const int orig = (t < nb) ? bsum[t] : 0;
    s[t] = orig;
    __syncthreads();
    for (int off = 1; off < 512; off <<= 1) {
        int v = (t >= off) ? s[t - off] : 0;
        __syncthreads();
        s[t] += v;
        __syncthreads();
    }
    if (t < nb) bsum[t] = s[t] - orig;   // exclusive
}

// ---------------- scan step 3: in-block exclusive scan + offset ----------------
__global__ __launch_bounds__(256) void scan3_kernel(const int* __restrict__ cnt,
                                                    const int* __restrict__ bsum,
                                                    int* __restrict__ row_start,
                                                    int* __restrict__ row_pos) {
    __shared__ int s[256];
    const int i = blockIdx.x * 256 + threadIdx.x;
    const int t = threadIdx.x;
    const int v = (i < M_NODES) ? cnt[i] : 0;
    s[t] = v;
    __syncthreads();
    for (int off = 1; off < 256; off <<= 1) {
        int u = (t >= off) ? s[t - off] : 0;
        __syncthreads();
        s[t] += u;
        __syncthreads();
    }
    if (i < M_NODES) {
        const int excl = s[t] - v + bsum[blockIdx.x];
        row_start[i] = excl;
        row_pos[i]   = excl;
    }
    if (i == 0) row_start[M_NODES] = N_EDGES;
}

// ---------------- CSR build: fill sorted (src, val) ----------------
__global__ __launch_bounds__(256) void fill_kernel(const int* __restrict__ rows,
                                                   const int* __restrict__ cols,
                                                   const float* __restrict__ vals,
                                                   int* __restrict__ row_pos,
                                                   int* __restrict__ ssrc,
                                                   float* __restrict__ sval) {
    const int e = blockIdx.x * 256 + threadIdx.x;
    if (e < N_EDGES) {
        const int dst = rows[e];
        const int p = atomicAdd(&row_pos[dst], 1);
        ssrc[p] = cols[e];
        sval[p] = vals[e];
    }
}

// ---------------- gather-reduce: one wave per row, fused finalize ----------------
__global__ __launch_bounds__(256) void gather_kernel(const float* __restrict__ support,
                                                     const int* __restrict__ row_start,
                                                     const int* __restrict__ ssrc,
                                                     const float* __restrict__ sval,
                                                     const float* __restrict__ norm,
                                                     const float* __restrict__ bias,
                                                     float* __restrict__ out) {
    const int row  = (blockIdx.x * 256 + threadIdx.x) >> 6;   // one wave per row
    const int lane = threadIdx.x & 63;
    if (row >= M_NODES) return;

    const int s0 = row_start[row];
    const int s1 = row_start[row + 1];
    const int fo = lane * 2;

    float2 acc = make_float2(0.f, 0.f);
    int j = s0;
    for (; j + 2 <= s1; j += 2) {
        const int   a  = ssrc[j];
        const int   b  = ssrc[j + 1];
        const float va = sval[j];
        const float vb = sval[j + 1];
        const float2 pa = *(const float2*)&support[(size_t)a * D + fo];
        const float2 pb = *(const float2*)&support[(size_t)b * D + fo];
        acc.x += pa.x * va; acc.y += pa.y * va;
        acc.x += pb.x * vb; acc.y += pb.y * vb;
    }
    if (j < s1) {
        const int   a  = ssrc[j];
        const float va = sval[j];
        const float2 pa = *(const float2*)&support[(size_t)a * D + fo];
        acc.x += pa.x * va; acc.y += pa.y * va;
    }

    const float inv = 1.0f / norm[row];
    const float2 b2 = *(const float2*)&bias[fo];
    float2 o;
    o.x = acc.x * inv + b2.x;
    o.y = acc.y * inv + b2.y;
    *(float2*)&out[(size_t)row * D + fo] = o;
}

// ---------------- fallback path (atomic scatter), used if ws too small ----------
__global__ __launch_bounds__(256) void spmm_kernel(const float* __restrict__ support,
                                                   const int* __restrict__ rows,
                                                   const int* __restrict__ cols,
                                                   const float* __restrict__ vals,
                                                   float* __restrict__ out) {
    const long long t = (long long)blockIdx.x * 256 + threadIdx.x;
    const int e = (int)(t >> 5);
    if (e >= N_EDGES) return;
    const int f   = (int)(t & 31) * 4;
    const int src = cols[e];
    const int dst = rows[e];
    const float v = vals[e];
    const float4 s = *(const float4*)&support[(size_t)src * D + f];
    float* o = &out[(size_t)dst * D + f];
    atomicAdd(o + 0, s.x * v);
    atomicAdd(o + 1, s.y * v);
    atomicAdd(o + 2, s.z * v);
    atomicAdd(o + 3, s.w * v);
}

__global__ __launch_bounds__(256) void finalize_kernel(float* __restrict__ out,
                                                       const float* __restrict__ norm,
                                                       const float* __restrict__ bias) {
    const int t = blockIdx.x * 256 + threadIdx.x;
    const int nrow = t >> 5;
    if (nrow >= M_NODES) return;
    const int f = (t & 31) * 4;
    const float inv = 1.0f / norm[nrow];
    float4 o = *(float4*)&out[(size_t)nrow * D + f];
    const float4 b = *(const float4*)&bias[f];
    o.x = o.x * inv + b.x;
    o.y = o.y * inv + b.y;
    o.z = o.z * inv + b.z;
    o.w = o.w * inv + b.w;
    *(float4*)&out[(size_t)nrow * D + f] = o;
}

extern "C" void kernel_launch(void* const* d_in, const int* in_sizes, int n_in,
                              void* d_out, int out_size, void* d_ws, size_t ws_size,
                              hipStream_t stream) {
    const float* x    = (const float*)d_in[0];
    const float* w    = (const float*)d_in[1];
    const float* bias = (const float*)d_in[2];
    const int*   rows = (const int*)d_in[3];
    const int*   cols = (const int*)d_in[4];
    const float* vals = (const float*)d_in[5];
    const float* norm = (const float*)d_in[6];
    float* out = (float*)d_out;

    char* ws = (char*)d_ws;
    float* support = (float*)(ws + OFF_SUPPORT);

    gemm_kernel<<<(M_NODES + 63) / 64, 256, 0, stream>>>(x, w, support, M_NODES);

    if (ws_size >= WS_NEEDED) {
        int*   cnt       = (int*)(ws + OFF_CNT);
        int*   row_start = (int*)(ws + OFF_START);
        int*   row_pos   = (int*)(ws + OFF_POS);
        int*   ssrc      = (int*)(ws + OFF_SRC);
        float* sval      = (float*)(ws + OFF_VAL);
        int*   bsum      = (int*)(ws + OFF_BSUM);

        hipMemsetAsync(cnt, 0, (size_t)M_NODES * sizeof(int), stream);

        const int eblocks = (N_EDGES + 255) / 256;
        hist_kernel<<<eblocks, 256, 0, stream>>>(rows, cnt);
        scan1_kernel<<<NBLK_SCAN, 256, 0, stream>>>(cnt, bsum);
        scan2_kernel<<<1, 512, 0, stream>>>(bsum, NBLK_SCAN);
        scan3_kernel<<<NBLK_SCAN, 256, 0, stream>>>(cnt, bsum, row_start, row_pos);
        fill_kernel<<<eblocks, 256, 0, stream>>>(rows, cols, vals, row_pos, ssrc, sval);

        const int gblocks = (M_NODES * 64 + 255) / 256;   // one wave per row
        gather_kernel<<<gblocks, 256, 0, stream>>>(support, row_start, ssrc, sval,
                                                   norm, bias, out);
    } else {
        // fallback: atomic scatter (needs only support in ws)
        hipMemsetAsync(d_out, 0, (size_t)out_size * sizeof(float), stream);
        const long long spmm_threads = (long long)N_EDGES * 32;
        spmm_kernel<<<(int)((spmm_threads + 255) / 256), 256, 0, stream>>>(support, rows, cols, vals, out);
        finalize_kernel<<<(M_NODES * 32 + 255) / 256, 256, 0, stream>>>(out, norm, bias);
    }
}

// Round 3
// 650.396 us; speedup vs baseline: 8.4702x; 1.1073x over previous
//
#include <hip/hip_runtime.h>

#define M_NODES 100000
#define N_EDGES 3200000
#define D 128

// ---------------- workspace layout (bytes) ----------------
// new path (bf16 support + packed edges):
#define OFF_SUP16   0ull            // 100000*128 bf16 = 25,600,000
#define OFF_CNT     25600000ull     // 100000 int
#define OFF_START   26000256ull     // 100001 int
#define OFF_POS     26400512ull     // 100000 int
#define OFF_EDGE    26800640ull     // 3.2M int2 = 25,600,000
#define OFF_BSUM    52400640ull     // 391 int (+pad)
#define WS_NEEDED   52402688ull

#define NBLK_SCAN 391   // ceil(100000/256)

__device__ __forceinline__ unsigned short f2bf(float f) {
    unsigned u = __float_as_uint(f);
    u += 0x7fff + ((u >> 16) & 1);      // round-to-nearest-even
    return (unsigned short)(u >> 16);
}
__device__ __forceinline__ float2 bfpair(unsigned u) {
    float2 r;
    r.x = __uint_as_float(u << 16);
    r.y = __uint_as_float(u & 0xffff0000u);
    return r;
}

// ---------------- GEMM: support(bf16) = x @ W  (M x 128) ----------------
__global__ __launch_bounds__(256) void gemm_kernel(const float* __restrict__ x,
                                                   const float* __restrict__ w,
                                                   unsigned* __restrict__ sup16,
                                                   int M) {
    __shared__ float sX[32][64];
    __shared__ float sW[32][128];

    const int tid = threadIdx.x;
    const int r0  = blockIdx.x * 64;
    const int tx  = tid & 31;
    const int ty  = tid >> 5;

    float acc[8][4];
#pragma unroll
    for (int r = 0; r < 8; ++r)
#pragma unroll
        for (int c = 0; c < 4; ++c) acc[r][c] = 0.f;

    for (int c0 = 0; c0 < 128; c0 += 32) {
        {
            const int row = tid >> 3;
            const int kk  = (tid & 7) * 4;
#pragma unroll
            for (int h = 0; h < 2; ++h) {
                const int rr = row + h * 32;
                float4 v = make_float4(0.f, 0.f, 0.f, 0.f);
                if (r0 + rr < M)
                    v = *(const float4*)&x[(size_t)(r0 + rr) * D + c0 + kk];
                sX[kk + 0][rr] = v.x;
                sX[kk + 1][rr] = v.y;
                sX[kk + 2][rr] = v.z;
                sX[kk + 3][rr] = v.w;
            }
        }
#pragma unroll
        for (int i = tid; i < 1024; i += 256) {
            const int k  = i >> 5;
            const int c4 = (i & 31) * 4;
            *(float4*)&sW[k][c4] = *(const float4*)&w[(size_t)(c0 + k) * D + c4];
        }
        __syncthreads();

#pragma unroll
        for (int k = 0; k < 32; ++k) {
            const float4 wv = *(const float4*)&sW[k][tx * 4];
            const float4 xa = *(const float4*)&sX[k][ty * 8];
            const float4 xb = *(const float4*)&sX[k][ty * 8 + 4];
            const float xr[8] = {xa.x, xa.y, xa.z, xa.w, xb.x, xb.y, xb.z, xb.w};
#pragma unroll
            for (int r = 0; r < 8; ++r) {
                acc[r][0] += xr[r] * wv.x;
                acc[r][1] += xr[r] * wv.y;
                acc[r][2] += xr[r] * wv.z;
                acc[r][3] += xr[r] * wv.w;
            }
        }
        __syncthreads();
    }

#pragma unroll
    for (int r = 0; r < 8; ++r) {
        const int row = r0 + ty * 8 + r;
        if (row < M) {
            uint2 p;
            p.x = (unsigned)f2bf(acc[r][0]) | ((unsigned)f2bf(acc[r][1]) << 16);
            p.y = (unsigned)f2bf(acc[r][2]) | ((unsigned)f2bf(acc[r][3]) << 16);
            *(uint2*)&sup16[(size_t)row * 64 + tx * 2] = p;
        }
    }
}

// ---------------- CSR build: histogram (4 edges/thread) ----------------
__global__ __launch_bounds__(256) void hist_kernel(const int* __restrict__ rows,
                                                   int* __restrict__ cnt) {
    const int i = (blockIdx.x * 256 + threadIdx.x) * 4;
    if (i >= N_EDGES) return;
    const int4 r = *(const int4*)&rows[i];
    atomicAdd(&cnt[r.x], 1);
    atomicAdd(&cnt[r.y], 1);
    atomicAdd(&cnt[r.z], 1);
    atomicAdd(&cnt[r.w], 1);
}

// ---------------- scan step 1: per-block sums ----------------
__global__ __launch_bounds__(256) void scan1_kernel(const int* __restrict__ cnt,
                                                    int* __restrict__ bsum) {
    __shared__ int s[256];
    const int i = blockIdx.x * 256 + threadIdx.x;
    s[threadIdx.x] = (i < M_NODES) ? cnt[i] : 0;
    __syncthreads();
    for (int off = 128; off > 0; off >>= 1) {
        if (threadIdx.x < off) s[threadIdx.x] += s[threadIdx.x + off];
        __syncthreads();
    }
    if (threadIdx.x == 0) bsum[blockIdx.x] = s[0];
}

// ---------------- scan step 2: scan block sums (single block) ----------------
__global__ __launch_bounds__(512) void scan2_kernel(int* __restrict__ bsum, int nb) {
    __shared__ int s[512];
    const int t = threadIdx.x;
    const int orig = (t < nb) ? bsum[t] : 0;
    s[t] = orig;
    __syncthreads();
    for (int off = 1; off < 512; off <<= 1) {
        int v = (t >= off) ? s[t - off] : 0;
        __syncthreads();
        s[t] += v;
        __syncthreads();
    }
    if (t < nb) bsum[t] = s[t] - orig;   // exclusive
}

// ---------------- scan step 3: in-block exclusive scan + offset ----------------
__global__ __launch_bounds__(256) void scan3_kernel(const int* __restrict__ cnt,
                                                    const int* __restrict__ bsum,
                                                    int* __restrict__ row_start,
                                                    int* __restrict__ row_pos) {
    __shared__ int s[256];
    const int i = blockIdx.x * 256 + threadIdx.x;
    const int t = threadIdx.x;
    const int v = (i < M_NODES) ? cnt[i] : 0;
    s[t] = v;
    __syncthreads();
    for (int off = 1; off < 256; off <<= 1) {
        int u = (t >= off) ? s[t - off] : 0;
        __syncthreads();
        s[t] += u;
        __syncthreads();
    }
    if (i < M_NODES) {
        const int excl = s[t] - v + bsum[blockIdx.x];
        row_start[i] = excl;
        row_pos[i]   = excl;
    }
    if (i == 0) row_start[M_NODES] = N_EDGES;
}

// ---------------- CSR build: fill packed (src, valbits) records ----------------
__global__ __launch_bounds__(256) void fill_kernel(const int* __restrict__ rows,
                                                   const int* __restrict__ cols,
                                                   const float* __restrict__ vals,
                                                   int* __restrict__ row_pos,
                                                   int2* __restrict__ edges) {
    const int i = (blockIdx.x * 256 + threadIdx.x) * 4;
    if (i >= N_EDGES) return;
    const int4   r = *(const int4*)&rows[i];
    const int4   c = *(const int4*)&cols[i];
    const float4 v = *(const float4*)&vals[i];
    int p;
    p = atomicAdd(&row_pos[r.x], 1); edges[p] = make_int2(c.x, __float_as_int(v.x));
    p = atomicAdd(&row_pos[r.y], 1); edges[p] = make_int2(c.y, __float_as_int(v.y));
    p = atomicAdd(&row_pos[r.z], 1); edges[p] = make_int2(c.z, __float_as_int(v.z));
    p = atomicAdd(&row_pos[r.w], 1); edges[p] = make_int2(c.w, __float_as_int(v.w));
}

// ---------------- gather-reduce: one wave per row, fused finalize ----------------
__global__ __launch_bounds__(256) void gather_kernel(const unsigned* __restrict__ sup16,
                                                     const int* __restrict__ row_start,
                                                     const int2* __restrict__ edges,
                                                     const float* __restrict__ norm,
                                                     const float* __restrict__ bias,
                                                     float* __restrict__ out) {
    const int row  = (blockIdx.x * 256 + threadIdx.x) >> 6;   // one wave per row
    const int lane = threadIdx.x & 63;
    if (row >= M_NODES) return;

    const int s0 = row_start[row];
    const int s1 = row_start[row + 1];

    float2 acc = make_float2(0.f, 0.f);
    int j = s0;
    for (; j + 4 <= s1; j += 4) {
        const int2 e0 = edges[j];
        const int2 e1 = edges[j + 1];
        const int2 e2 = edges[j + 2];
        const int2 e3 = edges[j + 3];
        const unsigned w0 = sup16[(size_t)e0.x * 64 + lane];
        const unsigned w1 = sup16[(size_t)e1.x * 64 + lane];
        const unsigned w2 = sup16[(size_t)e2.x * 64 + lane];
        const unsigned w3 = sup16[(size_t)e3.x * 64 + lane];
        const float v0 = __int_as_float(e0.y);
        const float v1 = __int_as_float(e1.y);
        const float v2 = __int_as_float(e2.y);
        const float v3 = __int_as_float(e3.y);
        float2 p;
        p = bfpair(w0); acc.x += p.x * v0; acc.y += p.y * v0;
        p = bfpair(w1); acc.x += p.x * v1; acc.y += p.y * v1;
        p = bfpair(w2); acc.x += p.x * v2; acc.y += p.y * v2;
        p = bfpair(w3); acc.x += p.x * v3; acc.y += p.y * v3;
    }
    for (; j < s1; ++j) {
        const int2 e = edges[j];
        const unsigned wv = sup16[(size_t)e.x * 64 + lane];
        const float v = __int_as_float(e.y);
        const float2 p = bfpair(wv);
        acc.x += p.x * v; acc.y += p.y * v;
    }

    const int fo = lane * 2;
    const float inv = 1.0f / norm[row];
    const float2 b2 = *(const float2*)&bias[fo];
    float2 o;
    o.x = acc.x * inv + b2.x;
    o.y = acc.y * inv + b2.y;
    *(float2*)&out[(size_t)row * D + fo] = o;
}

// ---------------- fallback path (atomic scatter on fp32 support) ----------------
__global__ __launch_bounds__(256) void gemm32_kernel(const float* __restrict__ x,
                                                     const float* __restrict__ w,
                                                     float* __restrict__ support,
                                                     int M) {
    __shared__ float sX[32][64];
    __shared__ float sW[32][128];
    const int tid = threadIdx.x;
    const int r0  = blockIdx.x * 64;
    const int tx  = tid & 31;
    const int ty  = tid >> 5;
    float acc[8][4];
#pragma unroll
    for (int r = 0; r < 8; ++r)
#pragma unroll
        for (int c = 0; c < 4; ++c) acc[r][c] = 0.f;
    for (int c0 = 0; c0 < 128; c0 += 32) {
        {
            const int row = tid >> 3;
            const int kk  = (tid & 7) * 4;
#pragma unroll
            for (int h = 0; h < 2; ++h) {
                const int rr = row + h * 32;
                float4 v = make_float4(0.f, 0.f, 0.f, 0.f);
                if (r0 + rr < M)
                    v = *(const float4*)&x[(size_t)(r0 + rr) * D + c0 + kk];
                sX[kk + 0][rr] = v.x; sX[kk + 1][rr] = v.y;
                sX[kk + 2][rr] = v.z; sX[kk + 3][rr] = v.w;
            }
        }
#pragma unroll
        for (int i = tid; i < 1024; i += 256) {
            const int k  = i >> 5;
            const int c4 = (i & 31) * 4;
            *(float4*)&sW[k][c4] = *(const float4*)&w[(size_t)(c0 + k) * D + c4];
        }
        __syncthreads();
#pragma unroll
        for (int k = 0; k < 32; ++k) {
            const float4 wv = *(const float4*)&sW[k][tx * 4];
            const float4 xa = *(const float4*)&sX[k][ty * 8];
            const float4 xb = *(const float4*)&sX[k][ty * 8 + 4];
            const float xr[8] = {xa.x, xa.y, xa.z, xa.w, xb.x, xb.y, xb.z, xb.w};
#pragma unroll
            for (int r = 0; r < 8; ++r) {
                acc[r][0] += xr[r] * wv.x; acc[r][1] += xr[r] * wv.y;
                acc[r][2] += xr[r] * wv.z; acc[r][3] += xr[r] * wv.w;
            }
        }
        __syncthreads();
    }
#pragma unroll
    for (int r = 0; r < 8; ++r) {
        const int row = r0 + ty * 8 + r;
        if (row < M)
            *(float4*)&support[(size_t)row * D + tx * 4] =
                make_float4(acc[r][0], acc[r][1], acc[r][2], acc[r][3]);
    }
}

__global__ __launch_bounds__(256) void spmm_kernel(const float* __restrict__ support,
                                                   const int* __restrict__ rows,
                                                   const int* __restrict__ cols,
                                                   const float* __restrict__ vals,
                                                   float* __restrict__ out) {
    const long long t = (long long)blockIdx.x * 256 + threadIdx.x;
    const int e = (int)(t >> 5);
    if (e >= N_EDGES) return;
    const int f   = (int)(t & 31) * 4;
    const int src = cols[e];
    const int dst = rows[e];
    const float v = vals[e];
    const float4 s = *(const float4*)&support[(size_t)src * D + f];
    float* o = &out[(size_t)dst * D + f];
    atomicAdd(o + 0, s.x * v);
    atomicAdd(o + 1, s.y * v);
    atomicAdd(o + 2, s.z * v);
    atomicAdd(o + 3, s.w * v);
}

__global__ __launch_bounds__(256) void finalize_kernel(float* __restrict__ out,
                                                       const float* __restrict__ norm,
                                                       const float* __restrict__ bias) {
    const int t = blockIdx.x * 256 + threadIdx.x;
    const int nrow = t >> 5;
    if (nrow >= M_NODES) return;
    const int f = (t & 31) * 4;
    const float inv = 1.0f / norm[nrow];
    float4 o = *(float4*)&out[(size_t)nrow * D + f];
    const float4 b = *(const float4*)&bias[f];
    o.x = o.x * inv + b.x; o.y = o.y * inv + b.y;
    o.z = o.z * inv + b.z; o.w = o.w * inv + b.w;
    *(float4*)&out[(size_t)nrow * D + f] = o;
}

extern "C" void kernel_launch(void* const* d_in, const int* in_sizes, int n_in,
                              void* d_out, int out_size, void* d_ws, size_t ws_size,
                              hipStream_t stream) {
    const float* x    = (const float*)d_in[0];
    const float* w    = (const float*)d_in[1];
    const float* bias = (const float*)d_in[2];
    const int*   rows = (const int*)d_in[3];
    const int*   cols = (const int*)d_in[4];
    const float* vals = (const float*)d_in[5];
    const float* norm = (const float*)d_in[6];
    float* out = (float*)d_out;
    char* ws = (char*)d_ws;

    if (ws_size >= WS_NEEDED) {
        unsigned* sup16     = (unsigned*)(ws + OFF_SUP16);
        int*      cnt       = (int*)(ws + OFF_CNT);
        int*      row_start = (int*)(ws + OFF_START);
        int*      row_pos   = (int*)(ws + OFF_POS);
        int2*     edges     = (int2*)(ws + OFF_EDGE);
        int*      bsum      = (int*)(ws + OFF_BSUM);

        gemm_kernel<<<(M_NODES + 63) / 64, 256, 0, stream>>>(x, w, sup16, M_NODES);

        hipMemsetAsync(cnt, 0, (size_t)M_NODES * sizeof(int), stream);
        const int e4blocks = (N_EDGES / 4 + 255) / 256;
        hist_kernel<<<e4blocks, 256, 0, stream>>>(rows, cnt);
        scan1_kernel<<<NBLK_SCAN, 256, 0, stream>>>(cnt, bsum);
        scan2_kernel<<<1, 512, 0, stream>>>(bsum, NBLK_SCAN);
        scan3_kernel<<<NBLK_SCAN, 256, 0, stream>>>(cnt, bsum, row_start, row_pos);
        fill_kernel<<<e4blocks, 256, 0, stream>>>(rows, cols, vals, row_pos, edges);

        const int gblocks = (M_NODES * 64 + 255) / 256;   // one wave per row
        gather_kernel<<<gblocks, 256, 0, stream>>>(sup16, row_start, edges,
                                                   norm, bias, out);
    } else {
        // fallback: fp32 support + atomic scatter
        float* support = (float*)ws;
        gemm32_kernel<<<(M_NODES + 63) / 64, 256, 0, stream>>>(x, w, support, M_NODES);
        hipMemsetAsync(d_out, 0, (size_t)out_size * sizeof(float), stream);
        const long long spmm_threads = (long long)N_EDGES * 32;
        spmm_kernel<<<(int)((spmm_threads + 255) / 256), 256, 0, stream>>>(support, rows, cols, vals, out);
        finalize_kernel<<<(M_NODES * 32 + 255) / 256, 256, 0, stream>>>(out, norm, bias);
    }
}